// Round 2
// baseline (240.577 us; speedup 1.0000x reference)
//
#include <hip/hip_runtime.h>

// Problem: B=4, S=4096, H=16, D=128 -> C=2048, K=4. All fp32.
// out[b,h,s,d] = silu( bias[c] + sum_{k=0..3} w[c,k] * x[b, s-3+k, c] ), c = h*128+d
// x layout: [B,S,C] contiguous; causal (zero left-pad).
// Round-1 post-mortem: NaN under bf16 interpretation proves inputs are raw fp32
// (fp32 mantissa bits read as bf16 hit exponent 0xFF ~ p=2^-8 -> NaNs). fp32 I/O here.

constexpr int Bb = 4, Ss = 4096, Hh = 16, Dd = 128, Cc = 2048, Kk = 4;
constexpr int SEQ = 32;    // s positions per block; halo = 3/SEQ ~ 9%
constexpr int CPB = 1024;  // channels per block (256 threads x 4 channels)

union F4 {
    float4 v;
    float f[4];
};

__global__ __launch_bounds__(256, 4) void titans_conv(
    const float* __restrict__ x,     // [B,S,C]
    const float* __restrict__ w,     // [C,K]
    const float* __restrict__ bias,  // [C]
    float* __restrict__ out)         // [B,H,S,D]
{
    const int t  = threadIdx.x;                      // 0..255
    const int c0 = (int)blockIdx.z * CPB + t * 4;    // 4 contiguous channels
    const int s0 = (int)blockIdx.x * SEQ;
    const int b  = (int)blockIdx.y;

    // ---- weights + bias into registers (once) ----
    float wf[4][4], bv[4];
    {
        const float4* wp = (const float4*)(w + (size_t)c0 * Kk);  // 16 contiguous floats
        #pragma unroll
        for (int j = 0; j < 4; ++j) {
            F4 u; u.v = wp[j];                        // channel c0+j, taps 0..3
            #pragma unroll
            for (int k = 0; k < 4; ++k) wf[j][k] = u.f[k];
        }
        F4 bu; bu.v = *(const float4*)(bias + c0);
        #pragma unroll
        for (int j = 0; j < 4; ++j) bv[j] = bu.f[j];
    }

    const float* xcol = x + (size_t)b * Ss * Cc + c0;   // row stride Cc

    // ---- rolling 3-deep window (zero-padded left edge) ----
    float xm3[4], xm2[4], xm1[4];
    {
        float* dst[3] = { xm3, xm2, xm1 };
        #pragma unroll
        for (int r = 0; r < 3; ++r) {
            int s = s0 - 3 + r;
            if (s >= 0) {
                F4 u; u.v = *(const float4*)(xcol + (size_t)s * Cc);
                #pragma unroll
                for (int j = 0; j < 4; ++j) dst[r][j] = u.f[j];
            } else {
                #pragma unroll
                for (int j = 0; j < 4; ++j) dst[r][j] = 0.f;
            }
        }
    }

    const int h = c0 >> 7;            // c0 / 128
    const int d = c0 & 127;
    float* orow = out + (((size_t)b * Hh + h) * Ss + s0) * Dd + d;

    #pragma unroll
    for (int i = 0; i < SEQ; ++i) {
        F4 u;
        u.v = *(const float4*)(xcol + (size_t)(s0 + i) * Cc);   // s0+i >= 0 always
        float xc[4];
        #pragma unroll
        for (int j = 0; j < 4; ++j) xc[j] = u.f[j];

        F4 res;
        #pragma unroll
        for (int j = 0; j < 4; ++j) {
            float z = bv[j];
            z = fmaf(wf[j][0], xm3[j], z);
            z = fmaf(wf[j][1], xm2[j], z);
            z = fmaf(wf[j][2], xm1[j], z);
            z = fmaf(wf[j][3], xc[j],  z);
            // silu(z) = z / (1 + exp(-z))
            float e = __expf(-z);
            res.f[j] = z * __builtin_amdgcn_rcpf(1.0f + e);
        }
        *(float4*)(orow + (size_t)i * Dd) = res.v;

        #pragma unroll
        for (int j = 0; j < 4; ++j) {   // rotate window (renamed by unroll)
            xm3[j] = xm2[j];
            xm2[j] = xm1[j];
            xm1[j] = xc[j];
        }
    }
}

extern "C" void kernel_launch(void* const* d_in, const int* in_sizes, int n_in,
                              void* d_out, int out_size, void* d_ws, size_t ws_size,
                              hipStream_t stream) {
    const float* x    = (const float*)d_in[0];   // hidden_states [B,S,H,D] = [B,S,C]
    const float* w    = (const float*)d_in[1];   // conv_weight [C,K]
    const float* bias = (const float*)d_in[2];   // conv_bias [C]
    float* out        = (float*)d_out;           // [B,H,S,D]

    dim3 grid(Ss / SEQ, Bb, Cc / CPB);  // 128 x 4 x 2 = 1024 blocks -> 4 blocks/CU
    titans_conv<<<grid, 256, 0, stream>>>(x, w, bias, out);
}

// Round 3
// 237.076 us; speedup vs baseline: 1.0148x; 1.0148x over previous
//
#include <hip/hip_runtime.h>

// Problem: B=4, S=4096, H=16, D=128 -> C=2048, K=4. All fp32.
// out[b,h,s,d] = silu( bias[c] + sum_{k=0..3} w[c,k] * x[b, s-3+k, c] ), c = h*128+d
// x layout: [B,S,C] contiguous; causal (zero left-pad).
//
// Round-2 post-mortem: rolling-window version was LATENCY-bound (2.5 TB/s, VGPR=32,
// VALUBusy 8.6%) — only ~4 loads in flight per wave. Harness memset hit 6.47 TB/s at
// 9% occupancy => BW needs outstanding requests, not occupancy. This version batches
// all 19 row-loads (halo+SEQ) up front -> 19 outstanding global_load_dwordx4/wave.

constexpr int Bb = 4, Ss = 4096, Hh = 16, Dd = 128, Cc = 2048, Kk = 4;
constexpr int SEQ = 16;    // s positions per block; 19 rows loaded up front
constexpr int CPB = 1024;  // channels per block (256 threads x 4 channels)

union F4 {
    float4 v;
    float f[4];
};

__global__ __launch_bounds__(256, 4) void titans_conv(
    const float* __restrict__ x,     // [B,S,C]
    const float* __restrict__ w,     // [C,K]
    const float* __restrict__ bias,  // [C]
    float* __restrict__ out)         // [B,H,S,D]
{
    const int t  = threadIdx.x;                      // 0..255
    const int c0 = (int)blockIdx.z * CPB + t * 4;    // 4 contiguous channels
    const int s0 = (int)blockIdx.x * SEQ;
    const int b  = (int)blockIdx.y;

    const float* xcol = x + (size_t)b * Ss * Cc + c0;   // row stride Cc

    // ---- batch-issue ALL row loads first: 19 outstanding dwordx4 ----
    F4 rows[SEQ + 3];
    if (s0 >= 3) {                                   // common case: no edge check
        #pragma unroll
        for (int r = 0; r < SEQ + 3; ++r)
            rows[r].v = *(const float4*)(xcol + (size_t)(s0 - 3 + r) * Cc);
    } else {                                         // blockIdx.x == 0: zero left-pad
        #pragma unroll
        for (int r = 0; r < 3; ++r) {
            rows[r].f[0] = rows[r].f[1] = rows[r].f[2] = rows[r].f[3] = 0.f;
        }
        #pragma unroll
        for (int r = 3; r < SEQ + 3; ++r)
            rows[r].v = *(const float4*)(xcol + (size_t)(s0 - 3 + r) * Cc);
    }

    // ---- weights + bias (tiny, L2-resident after first block) ----
    float wf[4][4], bv[4];
    {
        const float4* wp = (const float4*)(w + (size_t)c0 * Kk);  // 16 contiguous floats
        #pragma unroll
        for (int j = 0; j < 4; ++j) {
            F4 u; u.v = wp[j];                        // channel c0+j, taps 0..3
            #pragma unroll
            for (int k = 0; k < 4; ++k) wf[j][k] = u.f[k];
        }
        F4 bu; bu.v = *(const float4*)(bias + c0);
        #pragma unroll
        for (int j = 0; j < 4; ++j) bv[j] = bu.f[j];
    }

    const int h = c0 >> 7;            // c0 / 128
    const int d = c0 & 127;
    float* orow = out + (((size_t)b * Hh + h) * Ss + s0) * Dd + d;

    #pragma unroll
    for (int i = 0; i < SEQ; ++i) {
        F4 res;
        #pragma unroll
        for (int j = 0; j < 4; ++j) {
            float z = bv[j];
            z = fmaf(wf[j][0], rows[i + 0].f[j], z);
            z = fmaf(wf[j][1], rows[i + 1].f[j], z);
            z = fmaf(wf[j][2], rows[i + 2].f[j], z);
            z = fmaf(wf[j][3], rows[i + 3].f[j], z);
            // silu(z) = z / (1 + exp(-z))
            float e = __expf(-z);
            res.f[j] = z * __builtin_amdgcn_rcpf(1.0f + e);
        }
        *(float4*)(orow + (size_t)i * Dd) = res.v;
    }
}

extern "C" void kernel_launch(void* const* d_in, const int* in_sizes, int n_in,
                              void* d_out, int out_size, void* d_ws, size_t ws_size,
                              hipStream_t stream) {
    const float* x    = (const float*)d_in[0];   // hidden_states [B,S,H,D] = [B,S,C]
    const float* w    = (const float*)d_in[1];   // conv_weight [C,K]
    const float* bias = (const float*)d_in[2];   // conv_bias [C]
    float* out        = (float*)d_out;           // [B,H,S,D]

    dim3 grid(Ss / SEQ, Bb, Cc / CPB);  // 256 x 4 x 2 = 2048 blocks -> 8 blocks/CU
    titans_conv<<<grid, 256, 0, stream>>>(x, w, bias, out);
}

// Round 4
// 233.157 us; speedup vs baseline: 1.0318x; 1.0168x over previous
//
#include <hip/hip_runtime.h>

// Problem: B=4, S=4096, H=16, D=128 -> C=2048, K=4. All fp32.
// out[b,h,s,d] = silu( bias[c] + sum_{k=0..3} w[c,k] * x[b, s-3+k, c] ), c = h*128+d
// x layout: [B,S,C] contiguous; causal (zero left-pad).
//
// Round-3 post-mortem: compiler re-sank the batched loads (VGPR_Count stayed 32 ->
// <=4 loads in flight), so the MLP experiment never ran. This version pins the
// schedule with __builtin_amdgcn_sched_barrier(0): all 11 row loads MUST issue
// before any compute -> 11 outstanding global_load_dwordx4 per wave, ~44 payload
// VGPRs forced live. SEQ=8 keeps total VGPR ~85 < 128 cap (launch_bounds 256,4).

constexpr int Bb = 4, Ss = 4096, Hh = 16, Dd = 128, Cc = 2048, Kk = 4;
constexpr int SEQ = 8;     // s positions per block; 11 rows batch-loaded
constexpr int CPB = 1024;  // channels per block (256 threads x 4 channels)

union F4 {
    float4 v;
    float f[4];
};

__global__ __launch_bounds__(256, 4) void titans_conv(
    const float* __restrict__ x,     // [B,S,C]
    const float* __restrict__ w,     // [C,K]
    const float* __restrict__ bias,  // [C]
    float* __restrict__ out)         // [B,H,S,D]
{
    const int t  = threadIdx.x;                      // 0..255
    const int c0 = (int)blockIdx.z * CPB + t * 4;    // 4 contiguous channels
    const int s0 = (int)blockIdx.x * SEQ;
    const int b  = (int)blockIdx.y;

    const float* xcol = x + (size_t)b * Ss * Cc + c0;   // row stride Cc

    // ---- weights + bias first (L2-hot after first blocks, also in flight) ----
    float wf[4][4], bv[4];
    {
        const float4* wp = (const float4*)(w + (size_t)c0 * Kk);
        F4 u0, u1, u2, u3, ub;
        u0.v = wp[0]; u1.v = wp[1]; u2.v = wp[2]; u3.v = wp[3];
        ub.v = *(const float4*)(bias + c0);
        #pragma unroll
        for (int k = 0; k < 4; ++k) {
            wf[0][k] = u0.f[k]; wf[1][k] = u1.f[k];
            wf[2][k] = u2.f[k]; wf[3][k] = u3.f[k];
        }
        #pragma unroll
        for (int j = 0; j < 4; ++j) bv[j] = ub.f[j];
    }

    // ---- batch-issue ALL row loads; sched_barrier forbids sinking them ----
    F4 rows[SEQ + 3];
    if (s0 >= 3) {                                   // all blocks except blockIdx.x==0
        #pragma unroll
        for (int r = 0; r < SEQ + 3; ++r)
            rows[r].v = *(const float4*)(xcol + (size_t)(s0 - 3 + r) * Cc);
    } else {                                         // zero left-pad (block-uniform branch)
        #pragma unroll
        for (int r = 0; r < 3; ++r)
            rows[r].f[0] = rows[r].f[1] = rows[r].f[2] = rows[r].f[3] = 0.f;
        #pragma unroll
        for (int r = 3; r < SEQ + 3; ++r)
            rows[r].v = *(const float4*)(xcol + (size_t)(s0 - 3 + r) * Cc);
    }

    __builtin_amdgcn_sched_barrier(0);   // nothing moves across: loads stay batched

    const int h = c0 >> 7;            // c0 / 128
    const int d = c0 & 127;
    float* orow = out + (((size_t)b * Hh + h) * Ss + s0) * Dd + d;

    #pragma unroll
    for (int i = 0; i < SEQ; ++i) {
        F4 res;
        #pragma unroll
        for (int j = 0; j < 4; ++j) {
            float z = bv[j];
            z = fmaf(wf[j][0], rows[i + 0].f[j], z);
            z = fmaf(wf[j][1], rows[i + 1].f[j], z);
            z = fmaf(wf[j][2], rows[i + 2].f[j], z);
            z = fmaf(wf[j][3], rows[i + 3].f[j], z);
            // silu(z) = z / (1 + exp(-z))
            float e = __expf(-z);
            res.f[j] = z * __builtin_amdgcn_rcpf(1.0f + e);
        }
        *(float4*)(orow + (size_t)i * Dd) = res.v;
    }
}

extern "C" void kernel_launch(void* const* d_in, const int* in_sizes, int n_in,
                              void* d_out, int out_size, void* d_ws, size_t ws_size,
                              hipStream_t stream) {
    const float* x    = (const float*)d_in[0];   // hidden_states [B,S,H,D] = [B,S,C]
    const float* w    = (const float*)d_in[1];   // conv_weight [C,K]
    const float* bias = (const float*)d_in[2];   // conv_bias [C]
    float* out        = (float*)d_out;           // [B,H,S,D]

    dim3 grid(Ss / SEQ, Bb, Cc / CPB);  // 512 x 4 x 2 = 4096 blocks -> 16 blocks/CU queued
    titans_conv<<<grid, 256, 0, stream>>>(x, w, bias, out);
}